// Round 11
// baseline (326.641 us; speedup 1.0000x reference)
//
#include <hip/hip_runtime.h>

#define NF   32
#define NN1  64
#define NN2  128
#define P    66   // fp32 tile pitch; strided reads are 2-way-per-phase max (free)

typedef float f32x4 __attribute__((ext_vector_type(4)));
typedef short s16x8 __attribute__((ext_vector_type(8)));
typedef unsigned int u32;

__device__ __forceinline__ short f2bf(float f) {   // fp32 -> bf16 bits, RNE
    u32 u = __float_as_uint(f);
    return (short)((u + 0x7FFFu + ((u >> 16) & 1u)) >> 16);
}
__device__ __forceinline__ u32 pack2(float a, float b) {
    return (u32)(unsigned short)f2bf(a) | ((u32)(unsigned short)f2bf(b) << 16);
}

// D->B redistribution via XOR-only shuffles (conflict-free per 32-lane phase).
// Derived from the R10-validated lA/lB mapping:
//  w0: q0 self-L01, q1 ^48 L01, q2 ^32 H01, q3 ^16 H01
//  w2: q0 ^16 L01, q1 ^32 L01, q2 ^48 H01, q3 self-H01   (w1/w3 same on the 23 packs)
__device__ __forceinline__ s16x8 redist(u32 L01, u32 L23, u32 H01, u32 H23, int q) {
    u32 a0 = __shfl_xor((int)L01, 16), a1 = __shfl_xor((int)L01, 32), a2 = __shfl_xor((int)L01, 48);
    u32 b0 = __shfl_xor((int)L23, 16), b1 = __shfl_xor((int)L23, 32), b2 = __shfl_xor((int)L23, 48);
    u32 c0 = __shfl_xor((int)H01, 16), c1 = __shfl_xor((int)H01, 32), c2 = __shfl_xor((int)H01, 48);
    u32 d0 = __shfl_xor((int)H23, 16), d1 = __shfl_xor((int)H23, 32), d2 = __shfl_xor((int)H23, 48);
    u32 w0 = (q == 0) ? L01 : (q == 1) ? a2 : (q == 2) ? c1 : c0;
    u32 w1 = (q == 0) ? L23 : (q == 1) ? b2 : (q == 2) ? d1 : d0;
    u32 w2 = (q == 0) ? a0  : (q == 1) ? a1 : (q == 2) ? c2 : H01;
    u32 w3 = (q == 0) ? b0  : (q == 1) ? b1 : (q == 2) ? d2 : H23;
    s16x8 r;
    r[0] = (short)w0; r[1] = (short)(w0 >> 16);
    r[2] = (short)w1; r[3] = (short)(w1 >> 16);
    r[4] = (short)w2; r[5] = (short)(w2 >> 16);
    r[6] = (short)w3; r[7] = (short)(w3 >> 16);
    return r;
}

// 16 waves / block; wave w = (m = w&3, ng = w>>2): ONE n-group per wave so no
// state lives across ng iterations (R10 lesson: allocator pins 64 VGPR; fit it).
__global__ __launch_bounds__(1024, 4)
void v2b_fused(const float* __restrict__ xl,    // (B,32,128)
               const float* __restrict__ xo,    // (B,32,64)
               const float* __restrict__ txyz,  // (B,64,3)
               const float* __restrict__ mlp_w1, const float* __restrict__ mlp_s1, const float* __restrict__ mlp_t1,
               const float* __restrict__ mlp_w2, const float* __restrict__ mlp_s2, const float* __restrict__ mlp_t2,
               const float* __restrict__ gw_w1, const float* __restrict__ gw_b1,
               const float* __restrict__ gw_s,  const float* __restrict__ gw_t,
               const float* __restrict__ gw_w2, const float* __restrict__ gw_b2,
               const float* __restrict__ gm_w1, const float* __restrict__ gm_s1, const float* __restrict__ gm_t1,
               const float* __restrict__ gm_w2, const float* __restrict__ gm_s2, const float* __restrict__ gm_t2,
               const float* __restrict__ fl_w1, const float* __restrict__ fl_s1, const float* __restrict__ fl_t1,
               const float* __restrict__ fl_w2, const float* __restrict__ fl_b2,
               float* __restrict__ out)
{
    __shared__ float xo_s[NF][P];
    __shared__ float yon_s[NF][P];     // -(gw_w1 . xo)
    __shared__ float tpos_s[NF][P];    // gm_t1 + gm_s1*(gm_w1[:,0:3] . txyz)
    __shared__ float txyz_s[3][NN1];
    __shared__ float xl_s[NF][4];
    __shared__ float ylT_s[4][NF];     // gw_w1 . xl + gw_b1, [m][c]
    __shared__ float na_s[NN1];
    __shared__ float nb_s[4];
    __shared__ float gpart_s[16][NF];  // per-wave gpool partials
    __shared__ float gws_s[NF], gwt_s[NF], gwb2_s[NF], gmt2_s[NF];
    __shared__ s16x8 afrag_s[6][64];   // 0/1 gw2 lo/hi, 2/3 s1*gm1, 4/5 s2*gm2

    const int b    = blockIdx.x >> 5;
    const int m0   = (blockIdx.x & 31) * 4;
    const int tid  = threadIdx.x;
    const int lane = tid & 63;
    const int w    = tid >> 6;         // wave 0..15
    const int colr = lane & 15;
    const int q    = lane >> 4;
    const int mj   = w & 3;
    const int ng   = w >> 2;

    // ---- stage ----
    const float* xob = xo + (size_t)b * NF * NN1;
    for (int i = tid; i < NF * NN1; i += 1024) xo_s[i >> 6][i & 63] = xob[i];
    const float* tb = txyz + (size_t)b * NN1 * 3;
    if (tid < NN1 * 3) { int nn = tid / 3, k = tid % 3; txyz_s[k][nn] = tb[tid]; }
    if (tid < NF * 4) {
        int c = tid >> 2, j = tid & 3;
        xl_s[c][j] = xl[(size_t)b * NF * NN2 + c * NN2 + m0 + j];
    }
    if (tid < NF) {
        gws_s[tid]  = gw_s[tid];
        gwt_s[tid]  = gw_t[tid];
        gwb2_s[tid] = gw_b2[tid];
        gmt2_s[tid] = gm_t2[tid];
    }
    if (w < 6) {   // A-frags: no staged-data dependency
        const int f = w;
        const int row = (f & 1) ? colr + 16 : colr;
        s16x8 a;
        if (f < 2) {
            #pragma unroll
            for (int j = 0; j < 8; ++j) a[j] = f2bf(gw_w2[row * 32 + 8 * q + j]);
        } else if (f < 4) {
            const float s1 = gm_s1[row];
            #pragma unroll
            for (int j = 0; j < 8; ++j) a[j] = f2bf(s1 * gm_w1[row * 35 + 3 + 8 * q + j]);
        } else {
            const float s2 = gm_s2[row];
            #pragma unroll
            for (int j = 0; j < 8; ++j) a[j] = f2bf(s2 * gm_w2[row * 32 + 8 * q + j]);
        }
        afrag_s[f][lane] = a;
    }
    __syncthreads();

    // ---- block precompute (fp32 exact) ----
    for (int i = tid; i < NF * NN1; i += 1024) {
        const int o = i >> 6, nn = i & 63;
        float s = 0.f;
        #pragma unroll
        for (int c = 0; c < NF; ++c) s += gw_w1[o * 32 + c] * xo_s[c][nn];
        yon_s[o][nn] = -s;
        float tp = gm_w1[o * 35 + 0] * txyz_s[0][nn]
                 + gm_w1[o * 35 + 1] * txyz_s[1][nn]
                 + gm_w1[o * 35 + 2] * txyz_s[2][nn];
        tpos_s[o][nn] = gm_s1[o] * tp + gm_t1[o];
    }
    if (tid < 128) {
        const int o = tid >> 2, j = tid & 3;
        float s = gw_b1[o];
        #pragma unroll
        for (int c = 0; c < NF; ++c) s += gw_w1[o * 32 + c] * xl_s[c][j];
        ylT_s[j][o] = s;
    } else if (tid < 192) {
        const int nn = tid - 128;
        float s = 0.f;
        #pragma unroll
        for (int c = 0; c < NF; ++c) { float v = xo_s[c][nn]; s += v * v; }
        na_s[nn] = sqrtf(s);
    } else if (tid < 196) {
        const int j = tid - 192;
        float s = 0.f;
        #pragma unroll
        for (int c = 0; c < NF; ++c) { float v = xl_s[c][j]; s += v * v; }
        nb_s[j] = sqrtf(s);
    }
    __syncthreads();

    // ---- Phase A: one (m, ng) per wave ----
    {
        const int n = ng * 16 + colr;

        // B-frag g = leaky(gw_s*(yl+yon)+gw_t)
        s16x8 bg;
        #pragma unroll
        for (int j = 0; j < 8; ++j) {
            const int k = 8 * q + j;
            float y = yon_s[k][n] + ylT_s[mj][k];
            float a = gws_s[k] * y + gwt_s[k];
            bg[j] = f2bf(a > 0.f ? a : 0.2f * a);
        }

        // gate: z = gw_w2 @ g + b2
        f32x4 zlo, zhi;
        #pragma unroll
        for (int r = 0; r < 4; ++r) { zlo[r] = gwb2_s[4 * q + r]; zhi[r] = gwb2_s[4 * q + r + 16]; }
        zlo = __builtin_amdgcn_mfma_f32_16x16x32_bf16(afrag_s[0][lane], bg, zlo, 0, 0, 0);
        zhi = __builtin_amdgcn_mfma_f32_16x16x32_bf16(afrag_s[1][lane], bg, zhi, 0, 0, 0);

        // sigmoid * xo -> packs -> redistribute
        u32 L01, L23, H01, H23;
        {
            float d0 = xo_s[4 * q + 0][n] / (1.f + __expf(-zlo[0]));
            float d1 = xo_s[4 * q + 1][n] / (1.f + __expf(-zlo[1]));
            float d2 = xo_s[4 * q + 2][n] / (1.f + __expf(-zlo[2]));
            float d3 = xo_s[4 * q + 3][n] / (1.f + __expf(-zlo[3]));
            L01 = pack2(d0, d1); L23 = pack2(d2, d3);
            float e0 = xo_s[4 * q + 16][n] / (1.f + __expf(-zhi[0]));
            float e1 = xo_s[4 * q + 17][n] / (1.f + __expf(-zhi[1]));
            float e2 = xo_s[4 * q + 18][n] / (1.f + __expf(-zhi[2]));
            float e3 = xo_s[4 * q + 19][n] / (1.f + __expf(-zhi[3]));
            H01 = pack2(e0, e1); H23 = pack2(e2, e3);
        }
        s16x8 bga = redist(L01, L23, H01, H23, q);

        // gm1: m1 = relu(s1*(W@feat)+t1), txyz part in C-init
        f32x4 mlo, mhi;
        #pragma unroll
        for (int r = 0; r < 4; ++r) { mlo[r] = tpos_s[4 * q + r][n]; mhi[r] = tpos_s[4 * q + r + 16][n]; }
        mlo = __builtin_amdgcn_mfma_f32_16x16x32_bf16(afrag_s[2][lane], bga, mlo, 0, 0, 0);
        mhi = __builtin_amdgcn_mfma_f32_16x16x32_bf16(afrag_s[3][lane], bga, mhi, 0, 0, 0);

        u32 M01 = pack2(fmaxf(mlo[0], 0.f), fmaxf(mlo[1], 0.f));
        u32 M23 = pack2(fmaxf(mlo[2], 0.f), fmaxf(mlo[3], 0.f));
        u32 N01 = pack2(fmaxf(mhi[0], 0.f), fmaxf(mhi[1], 0.f));
        u32 N23 = pack2(fmaxf(mhi[2], 0.f), fmaxf(mhi[3], 0.f));
        s16x8 bm1 = redist(M01, M23, N01, N23, q);

        // gm2: relu(s2*(W@m1)+t2) -> per-channel max over this ng's 16 cols
        f32x4 plo, phi;
        #pragma unroll
        for (int r = 0; r < 4; ++r) { plo[r] = gmt2_s[4 * q + r]; phi[r] = gmt2_s[4 * q + r + 16]; }
        plo = __builtin_amdgcn_mfma_f32_16x16x32_bf16(afrag_s[4][lane], bm1, plo, 0, 0, 0);
        phi = __builtin_amdgcn_mfma_f32_16x16x32_bf16(afrag_s[5][lane], bm1, phi, 0, 0, 0);

        float rmax[8];
        #pragma unroll
        for (int r = 0; r < 4; ++r) {
            rmax[r]     = fmaxf(plo[r], 0.f);
            rmax[r + 4] = fmaxf(phi[r], 0.f);
        }
        #pragma unroll
        for (int ix = 0; ix < 8; ++ix) {
            float v = rmax[ix];
            v = fmaxf(v, __shfl_xor(v, 1));
            v = fmaxf(v, __shfl_xor(v, 2));
            v = fmaxf(v, __shfl_xor(v, 4));
            v = fmaxf(v, __shfl_xor(v, 8));
            rmax[ix] = v;
        }
        if (colr == 0) {
            #pragma unroll
            for (int ix = 0; ix < 8; ++ix)
                gpart_s[w][4 * q + (ix & 3) + 16 * (ix >> 2)] = rmax[ix];
        }
    }
    __syncthreads();

    // ---- Phase B: waves 0..3 only (one m each) ----
    if (w >= 4) return;
    const int m = m0 + mj;
    const int n = lane;
    float num = 0.f;
    #pragma unroll
    for (int c = 0; c < NF; ++c) num += xo_s[c][n] * xl_s[c][mj];
    float cosv = num / fmaxf(na_s[n] * nb_s[mj], 1e-8f);
    float mv = cosv; int mi = n;
    #pragma unroll
    for (int s = 32; s > 0; s >>= 1) {
        float ov = __shfl_xor(mv, s);
        int   oi = __shfl_xor(mi, s);
        if (ov > mv || (ov == mv && oi < mi)) { mv = ov; mi = oi; }
    }

    const int oc = lane & 31;
    float h1;
    {
        const float* wp = mlp_w1 + oc * 68;
        float acc = wp[0] * mv;
        #pragma unroll
        for (int k = 0; k < 3; ++k)  acc += wp[1 + k]  * txyz_s[k][mi];
        #pragma unroll
        for (int c = 0; c < 32; ++c) acc += wp[4 + c]  * xo_s[c][mi];
        #pragma unroll
        for (int c = 0; c < 32; ++c) acc += wp[36 + c] * xl_s[c][mj];
        acc = mlp_s1[oc] * acc + mlp_t1[oc];
        h1 = acc > 0.f ? acc : 0.f;
    }
    float h2;
    {
        const float* wp = mlp_w2 + oc * 32;
        float acc = 0.f;
        #pragma unroll
        for (int c = 0; c < 32; ++c) acc += wp[c] * __shfl(h1, c);
        acc = mlp_s2[oc] * acc + mlp_t2[oc];
        h2 = acc > 0.f ? acc : 0.f;
    }
    float o1;
    {
        const float* wp = fl_w1 + lane * 64;
        float acc = 0.f;
        #pragma unroll
        for (int c = 0; c < 32; ++c) acc += wp[c] * __shfl(h2, c);
        #pragma unroll
        for (int c = 0; c < 32; ++c) {
            float gv = fmaxf(fmaxf(gpart_s[mj][c], gpart_s[mj + 4][c]),
                             fmaxf(gpart_s[mj + 8][c], gpart_s[mj + 12][c]));
            acc += wp[32 + c] * gv;
        }
        acc = fl_s1[lane] * acc + fl_t1[lane];
        o1 = acc > 0.f ? acc : 0.f;
    }
    {
        const float* wp = fl_w2 + lane * 64;
        float acc = fl_b2[lane];
        #pragma unroll
        for (int c = 0; c < 64; ++c) acc += wp[c] * __shfl(o1, c);
        out[(size_t)b * 64 * NN2 + (size_t)lane * NN2 + m] = acc;
    }
}

extern "C" void kernel_launch(void* const* d_in, const int* in_sizes, int n_in,
                              void* d_out, int out_size, void* d_ws, size_t ws_size,
                              hipStream_t stream) {
    const float* xl     = (const float*)d_in[0];
    const float* xo     = (const float*)d_in[1];
    const float* txyz   = (const float*)d_in[2];
    const float* mlp_w1 = (const float*)d_in[3];
    const float* mlp_s1 = (const float*)d_in[4];
    const float* mlp_t1 = (const float*)d_in[5];
    const float* mlp_w2 = (const float*)d_in[6];
    const float* mlp_s2 = (const float*)d_in[7];
    const float* mlp_t2 = (const float*)d_in[8];
    const float* gw_w1  = (const float*)d_in[9];
    const float* gw_b1  = (const float*)d_in[10];
    const float* gw_s   = (const float*)d_in[11];
    const float* gw_t   = (const float*)d_in[12];
    const float* gw_w2  = (const float*)d_in[13];
    const float* gw_b2  = (const float*)d_in[14];
    const float* gm_w1  = (const float*)d_in[15];
    const float* gm_s1  = (const float*)d_in[16];
    const float* gm_t1  = (const float*)d_in[17];
    const float* gm_w2  = (const float*)d_in[18];
    const float* gm_s2  = (const float*)d_in[19];
    const float* gm_t2  = (const float*)d_in[20];
    const float* fl_w1  = (const float*)d_in[21];
    const float* fl_s1  = (const float*)d_in[22];
    const float* fl_t1  = (const float*)d_in[23];
    const float* fl_w2  = (const float*)d_in[24];
    const float* fl_b2  = (const float*)d_in[25];
    float* outp = (float*)d_out;

    const int B = in_sizes[0] / (NF * NN2);   // 128
    v2b_fused<<<dim3(B * 32), 1024, 0, stream>>>(
        xl, xo, txyz,
        mlp_w1, mlp_s1, mlp_t1, mlp_w2, mlp_s2, mlp_t2,
        gw_w1, gw_b1, gw_s, gw_t, gw_w2, gw_b2,
        gm_w1, gm_s1, gm_t1, gm_w2, gm_s2, gm_t2,
        fl_w1, fl_s1, fl_t1, fl_w2, fl_b2,
        outp);
}

// Round 12
// 270.165 us; speedup vs baseline: 1.2090x; 1.2090x over previous
//
#include <hip/hip_runtime.h>

#define NF   32
#define NN1  64
#define NN2  128
#define MT   16    // m per block
#define P    66    // fp32 tile pitch

typedef float f32x4 __attribute__((ext_vector_type(4)));
typedef short s16x8 __attribute__((ext_vector_type(8)));
typedef unsigned int u32;

__device__ __forceinline__ short f2bf(float f) {   // fp32 -> bf16, RNE
    u32 u = __float_as_uint(f);
    return (short)((u + 0x7FFFu + ((u >> 16) & 1u)) >> 16);
}
__device__ __forceinline__ u32 pack2(float a, float b) {
    return (u32)(unsigned short)f2bf(a) | ((u32)(unsigned short)f2bf(b) << 16);
}

// D->B redistribution, XOR-only (validated R11, absmax 1.95e-3)
__device__ __forceinline__ s16x8 redist(u32 L01, u32 L23, u32 H01, u32 H23, int q) {
    u32 a0 = __shfl_xor((int)L01, 16), a1 = __shfl_xor((int)L01, 32), a2 = __shfl_xor((int)L01, 48);
    u32 b0 = __shfl_xor((int)L23, 16), b1 = __shfl_xor((int)L23, 32), b2 = __shfl_xor((int)L23, 48);
    u32 c0 = __shfl_xor((int)H01, 16), c1 = __shfl_xor((int)H01, 32), c2 = __shfl_xor((int)H01, 48);
    u32 d0 = __shfl_xor((int)H23, 16), d1 = __shfl_xor((int)H23, 32), d2 = __shfl_xor((int)H23, 48);
    u32 w0 = (q == 0) ? L01 : (q == 1) ? a2 : (q == 2) ? c1 : c0;
    u32 w1 = (q == 0) ? L23 : (q == 1) ? b2 : (q == 2) ? d1 : d0;
    u32 w2 = (q == 0) ? a0  : (q == 1) ? a1 : (q == 2) ? c2 : H01;
    u32 w3 = (q == 0) ? b0  : (q == 1) ? b1 : (q == 2) ? d2 : H23;
    s16x8 r;
    r[0] = (short)w0; r[1] = (short)(w0 >> 16);
    r[2] = (short)w1; r[3] = (short)(w1 >> 16);
    r[4] = (short)w2; r[5] = (short)(w2 >> 16);
    r[6] = (short)w3; r[7] = (short)(w3 >> 16);
    return r;
}

// Block = 16 waves, covers 16 m. Phase A: 64 (m,ng) tasks, 4 iters/wave, no
// cross-iteration state (R11 lesson: fits 64-VGPR bucket, 40 used, no spill).
// Phase B: 16 m on 16 waves (R11 lesson: 4/16 active wasted 75%).
// A-frags duplicated in LDS, indexed by iter parity -> LICM can't hoist (R10 spill source).
__global__ __launch_bounds__(1024, 2)
void v2b_fused(const float* __restrict__ xl,    // (B,32,128)
               const float* __restrict__ xo,    // (B,32,64)
               const float* __restrict__ txyz,  // (B,64,3)
               const float* __restrict__ mlp_w1, const float* __restrict__ mlp_s1, const float* __restrict__ mlp_t1,
               const float* __restrict__ mlp_w2, const float* __restrict__ mlp_s2, const float* __restrict__ mlp_t2,
               const float* __restrict__ gw_w1, const float* __restrict__ gw_b1,
               const float* __restrict__ gw_s,  const float* __restrict__ gw_t,
               const float* __restrict__ gw_w2, const float* __restrict__ gw_b2,
               const float* __restrict__ gm_w1, const float* __restrict__ gm_s1, const float* __restrict__ gm_t1,
               const float* __restrict__ gm_w2, const float* __restrict__ gm_s2, const float* __restrict__ gm_t2,
               const float* __restrict__ fl_w1, const float* __restrict__ fl_s1, const float* __restrict__ fl_t1,
               const float* __restrict__ fl_w2, const float* __restrict__ fl_b2,
               float* __restrict__ out)
{
    __shared__ float xo_s[NF][P];
    __shared__ float yon_s[NF][P];       // -(gw_w1 . xo)
    __shared__ float tpos_s[NF][P];      // gm_t1 + gm_s1*(gm_w1[:,0:3] . txyz)
    __shared__ float txyz_s[3][NN1];
    __shared__ float xl_s[NF][MT];
    __shared__ float ylT_s[MT][NF];      // gw_w1 . xl + gw_b1, [m][c]
    __shared__ float na_s[NN1];
    __shared__ float nb_s[MT];
    __shared__ float gpart_s[MT][4][NF]; // per-(m,ng) gpool partials
    __shared__ float gws_s[NF], gwt_s[NF], gwb2_s[NF], gmt2_s[NF];
    __shared__ s16x8 afrag_s[2][6][64];  // duplicated: index by iter parity

    const int b    = blockIdx.x >> 3;          // 128 batches
    const int m0   = (blockIdx.x & 7) * MT;    // 8 m-tiles of 16
    const int tid  = threadIdx.x;
    const int lane = tid & 63;
    const int w    = tid >> 6;                 // wave 0..15
    const int colr = lane & 15;
    const int q    = lane >> 4;

    // ---- stage ----
    const float* xob = xo + (size_t)b * NF * NN1;
    for (int i = tid; i < NF * NN1; i += 1024) xo_s[i >> 6][i & 63] = xob[i];
    const float* tb = txyz + (size_t)b * NN1 * 3;
    if (tid < NN1 * 3) { int nn = tid / 3, k = tid % 3; txyz_s[k][nn] = tb[tid]; }
    if (tid < NF * MT) {
        int c = tid >> 4, j = tid & 15;
        xl_s[c][j] = xl[(size_t)b * NF * NN2 + c * NN2 + m0 + j];
    }
    if (tid >= 512 && tid < 512 + NF) {
        int c = tid - 512;
        gws_s[c]  = gw_s[c];
        gwt_s[c]  = gw_t[c];
        gwb2_s[c] = gw_b2[c];
        gmt2_s[c] = gm_t2[c];
    }
    if (w >= 8 && w < 14) {   // A-frags: no staged-data dependency
        const int f = w - 8;
        const int row = (f & 1) ? colr + 16 : colr;
        s16x8 a;
        if (f < 2) {
            #pragma unroll
            for (int j = 0; j < 8; ++j) a[j] = f2bf(gw_w2[row * 32 + 8 * q + j]);
        } else if (f < 4) {
            const float s1 = gm_s1[row];
            #pragma unroll
            for (int j = 0; j < 8; ++j) a[j] = f2bf(s1 * gm_w1[row * 35 + 3 + 8 * q + j]);
        } else {
            const float s2 = gm_s2[row];
            #pragma unroll
            for (int j = 0; j < 8; ++j) a[j] = f2bf(s2 * gm_w2[row * 32 + 8 * q + j]);
        }
        afrag_s[0][f][lane] = a;
        afrag_s[1][f][lane] = a;
    }
    __syncthreads();

    // ---- block precompute (fp32 exact) ----
    for (int i = tid; i < NF * NN1; i += 1024) {
        const int o = i >> 6, nn = i & 63;
        float s = 0.f;
        #pragma unroll
        for (int c = 0; c < NF; ++c) s += gw_w1[o * 32 + c] * xo_s[c][nn];
        yon_s[o][nn] = -s;
        float tp = gm_w1[o * 35 + 0] * txyz_s[0][nn]
                 + gm_w1[o * 35 + 1] * txyz_s[1][nn]
                 + gm_w1[o * 35 + 2] * txyz_s[2][nn];
        tpos_s[o][nn] = gm_s1[o] * tp + gm_t1[o];
    }
    if (tid < NF * MT) {
        const int j = tid >> 5, o = tid & 31;
        float s = gw_b1[o];
        #pragma unroll
        for (int c = 0; c < NF; ++c) s += gw_w1[o * 32 + c] * xl_s[c][j];
        ylT_s[j][o] = s;
    } else if (tid < NF * MT + NN1) {
        const int nn = tid - NF * MT;
        float s = 0.f;
        #pragma unroll
        for (int c = 0; c < NF; ++c) { float v = xo_s[c][nn]; s += v * v; }
        na_s[nn] = sqrtf(s);
    } else if (tid < NF * MT + NN1 + MT) {
        const int j = tid - NF * MT - NN1;
        float s = 0.f;
        #pragma unroll
        for (int c = 0; c < NF; ++c) { float v = xl_s[c][j]; s += v * v; }
        nb_s[j] = sqrtf(s);
    }
    __syncthreads();

    // ---- Phase A: 64 (m,ng) tasks over 16 waves ----
    for (int t = w; t < MT * 4; t += 16) {
        const int mj = t >> 2;
        const int ng = t & 3;
        const int n  = ng * 16 + colr;
        const s16x8* af = &afrag_s[(t >> 4) & 1][0][0];   // parity-indexed copy

        // B-frag g = leaky(gw_s*(yl+yon)+gw_t)
        s16x8 bg;
        #pragma unroll
        for (int j = 0; j < 8; ++j) {
            const int k = 8 * q + j;
            float y = yon_s[k][n] + ylT_s[mj][k];
            float a = gws_s[k] * y + gwt_s[k];
            bg[j] = f2bf(a > 0.f ? a : 0.2f * a);
        }

        // gate: z = gw_w2 @ g + b2
        f32x4 zlo, zhi;
        #pragma unroll
        for (int r = 0; r < 4; ++r) { zlo[r] = gwb2_s[4 * q + r]; zhi[r] = gwb2_s[4 * q + r + 16]; }
        zlo = __builtin_amdgcn_mfma_f32_16x16x32_bf16(af[0 * 64 + lane], bg, zlo, 0, 0, 0);
        zhi = __builtin_amdgcn_mfma_f32_16x16x32_bf16(af[1 * 64 + lane], bg, zhi, 0, 0, 0);

        // sigmoid * xo -> packs -> redistribute
        u32 L01, L23, H01, H23;
        {
            float d0 = xo_s[4 * q + 0][n] / (1.f + __expf(-zlo[0]));
            float d1 = xo_s[4 * q + 1][n] / (1.f + __expf(-zlo[1]));
            float d2 = xo_s[4 * q + 2][n] / (1.f + __expf(-zlo[2]));
            float d3 = xo_s[4 * q + 3][n] / (1.f + __expf(-zlo[3]));
            L01 = pack2(d0, d1); L23 = pack2(d2, d3);
            float e0 = xo_s[4 * q + 16][n] / (1.f + __expf(-zhi[0]));
            float e1 = xo_s[4 * q + 17][n] / (1.f + __expf(-zhi[1]));
            float e2 = xo_s[4 * q + 18][n] / (1.f + __expf(-zhi[2]));
            float e3 = xo_s[4 * q + 19][n] / (1.f + __expf(-zhi[3]));
            H01 = pack2(e0, e1); H23 = pack2(e2, e3);
        }
        s16x8 bga = redist(L01, L23, H01, H23, q);

        // gm1 (txyz part in C-init)
        f32x4 mlo, mhi;
        #pragma unroll
        for (int r = 0; r < 4; ++r) { mlo[r] = tpos_s[4 * q + r][n]; mhi[r] = tpos_s[4 * q + r + 16][n]; }
        mlo = __builtin_amdgcn_mfma_f32_16x16x32_bf16(af[2 * 64 + lane], bga, mlo, 0, 0, 0);
        mhi = __builtin_amdgcn_mfma_f32_16x16x32_bf16(af[3 * 64 + lane], bga, mhi, 0, 0, 0);

        u32 M01 = pack2(fmaxf(mlo[0], 0.f), fmaxf(mlo[1], 0.f));
        u32 M23 = pack2(fmaxf(mlo[2], 0.f), fmaxf(mlo[3], 0.f));
        u32 N01 = pack2(fmaxf(mhi[0], 0.f), fmaxf(mhi[1], 0.f));
        u32 N23 = pack2(fmaxf(mhi[2], 0.f), fmaxf(mhi[3], 0.f));
        s16x8 bm1 = redist(M01, M23, N01, N23, q);

        // gm2 -> per-channel max over this ng's 16 cols
        f32x4 plo, phi;
        #pragma unroll
        for (int r = 0; r < 4; ++r) { plo[r] = gmt2_s[4 * q + r]; phi[r] = gmt2_s[4 * q + r + 16]; }
        plo = __builtin_amdgcn_mfma_f32_16x16x32_bf16(af[4 * 64 + lane], bm1, plo, 0, 0, 0);
        phi = __builtin_amdgcn_mfma_f32_16x16x32_bf16(af[5 * 64 + lane], bm1, phi, 0, 0, 0);

        float rmax[8];
        #pragma unroll
        for (int r = 0; r < 4; ++r) {
            rmax[r]     = fmaxf(plo[r], 0.f);
            rmax[r + 4] = fmaxf(phi[r], 0.f);
        }
        #pragma unroll
        for (int ix = 0; ix < 8; ++ix) {
            float v = rmax[ix];
            v = fmaxf(v, __shfl_xor(v, 1));
            v = fmaxf(v, __shfl_xor(v, 2));
            v = fmaxf(v, __shfl_xor(v, 4));
            v = fmaxf(v, __shfl_xor(v, 8));
            rmax[ix] = v;
        }
        if (colr == 0) {
            #pragma unroll
            for (int ix = 0; ix < 8; ++ix)
                gpart_s[mj][ng][4 * q + (ix & 3) + 16 * (ix >> 2)] = rmax[ix];
        }
    }
    __syncthreads();

    // ---- Phase B: all 16 waves, wave w = m-slot w ----
    const int mj = w;
    const int m  = m0 + w;
    const int n  = lane;
    float num = 0.f;
    #pragma unroll
    for (int c = 0; c < NF; ++c) num += xo_s[c][n] * xl_s[c][mj];
    float cosv = num / fmaxf(na_s[n] * nb_s[mj], 1e-8f);
    float mv = cosv; int mi = n;
    #pragma unroll
    for (int s = 32; s > 0; s >>= 1) {
        float ov = __shfl_xor(mv, s);
        int   oi = __shfl_xor(mi, s);
        if (ov > mv || (ov == mv && oi < mi)) { mv = ov; mi = oi; }
    }

    const int oc = lane & 31;
    float h1;
    {
        const float* wp = mlp_w1 + oc * 68;
        float acc = wp[0] * mv;
        #pragma unroll
        for (int k = 0; k < 3; ++k)  acc += wp[1 + k]  * txyz_s[k][mi];
        #pragma unroll
        for (int c = 0; c < 32; ++c) acc += wp[4 + c]  * xo_s[c][mi];
        #pragma unroll
        for (int c = 0; c < 32; ++c) acc += wp[36 + c] * xl_s[c][mj];
        acc = mlp_s1[oc] * acc + mlp_t1[oc];
        h1 = acc > 0.f ? acc : 0.f;
    }
    float h2;
    {
        const float* wp = mlp_w2 + oc * 32;
        float acc = 0.f;
        #pragma unroll
        for (int c = 0; c < 32; ++c) acc += wp[c] * __shfl(h1, c);
        acc = mlp_s2[oc] * acc + mlp_t2[oc];
        h2 = acc > 0.f ? acc : 0.f;
    }
    float o1;
    {
        const float* wp = fl_w1 + lane * 64;
        float acc = 0.f;
        #pragma unroll
        for (int c = 0; c < 32; ++c) acc += wp[c] * __shfl(h2, c);
        #pragma unroll
        for (int c = 0; c < 32; ++c) {
            float gv = fmaxf(fmaxf(gpart_s[mj][0][c], gpart_s[mj][1][c]),
                             fmaxf(gpart_s[mj][2][c], gpart_s[mj][3][c]));
            acc += wp[32 + c] * gv;
        }
        acc = fl_s1[lane] * acc + fl_t1[lane];
        o1 = acc > 0.f ? acc : 0.f;
    }
    {
        const float* wp = fl_w2 + lane * 64;
        float acc = fl_b2[lane];
        #pragma unroll
        for (int c = 0; c < 64; ++c) acc += wp[c] * __shfl(o1, c);
        out[(size_t)b * 64 * NN2 + (size_t)lane * NN2 + m] = acc;
    }
}

extern "C" void kernel_launch(void* const* d_in, const int* in_sizes, int n_in,
                              void* d_out, int out_size, void* d_ws, size_t ws_size,
                              hipStream_t stream) {
    const float* xl     = (const float*)d_in[0];
    const float* xo     = (const float*)d_in[1];
    const float* txyz   = (const float*)d_in[2];
    const float* mlp_w1 = (const float*)d_in[3];
    const float* mlp_s1 = (const float*)d_in[4];
    const float* mlp_t1 = (const float*)d_in[5];
    const float* mlp_w2 = (const float*)d_in[6];
    const float* mlp_s2 = (const float*)d_in[7];
    const float* mlp_t2 = (const float*)d_in[8];
    const float* gw_w1  = (const float*)d_in[9];
    const float* gw_b1  = (const float*)d_in[10];
    const float* gw_s   = (const float*)d_in[11];
    const float* gw_t   = (const float*)d_in[12];
    const float* gw_w2  = (const float*)d_in[13];
    const float* gw_b2  = (const float*)d_in[14];
    const float* gm_w1  = (const float*)d_in[15];
    const float* gm_s1  = (const float*)d_in[16];
    const float* gm_t1  = (const float*)d_in[17];
    const float* gm_w2  = (const float*)d_in[18];
    const float* gm_s2  = (const float*)d_in[19];
    const float* gm_t2  = (const float*)d_in[20];
    const float* fl_w1  = (const float*)d_in[21];
    const float* fl_s1  = (const float*)d_in[22];
    const float* fl_t1  = (const float*)d_in[23];
    const float* fl_w2  = (const float*)d_in[24];
    const float* fl_b2  = (const float*)d_in[25];
    float* outp = (float*)d_out;

    const int B = in_sizes[0] / (NF * NN2);   // 128
    v2b_fused<<<dim3(B * 8), 1024, 0, stream>>>(
        xl, xo, txyz,
        mlp_w1, mlp_s1, mlp_t1, mlp_w2, mlp_s2, mlp_t2,
        gw_w1, gw_b1, gw_s, gw_t, gw_w2, gw_b2,
        gm_w1, gm_s1, gm_t1, gm_w2, gm_s2, gm_t2,
        fl_w1, fl_s1, fl_t1, fl_w2, fl_b2,
        outp);
}

// Round 13
// 240.304 us; speedup vs baseline: 1.3593x; 1.1243x over previous
//
#include <hip/hip_runtime.h>

#define NF   32
#define NN1  64
#define NN2  128
#define MT   16    // m per block
#define P    66    // fp32 tile pitch

typedef float f32x4 __attribute__((ext_vector_type(4)));
typedef short s16x8 __attribute__((ext_vector_type(8)));
typedef unsigned int u32;

__device__ __forceinline__ short f2bf(float f) {   // fp32 -> bf16, RNE
    u32 u = __float_as_uint(f);
    return (short)((u + 0x7FFFu + ((u >> 16) & 1u)) >> 16);
}
__device__ __forceinline__ u32 pack2(float a, float b) {
    return (u32)(unsigned short)f2bf(a) | ((u32)(unsigned short)f2bf(b) << 16);
}

// D->B redistribution, XOR-only (validated R11/R12, absmax 1.95e-3)
__device__ __forceinline__ s16x8 redist(u32 L01, u32 L23, u32 H01, u32 H23, int q) {
    u32 a0 = __shfl_xor((int)L01, 16), a1 = __shfl_xor((int)L01, 32), a2 = __shfl_xor((int)L01, 48);
    u32 b0 = __shfl_xor((int)L23, 16), b1 = __shfl_xor((int)L23, 32), b2 = __shfl_xor((int)L23, 48);
    u32 c0 = __shfl_xor((int)H01, 16), c1 = __shfl_xor((int)H01, 32), c2 = __shfl_xor((int)H01, 48);
    u32 d0 = __shfl_xor((int)H23, 16), d1 = __shfl_xor((int)H23, 32), d2 = __shfl_xor((int)H23, 48);
    u32 w0 = (q == 0) ? L01 : (q == 1) ? a2 : (q == 2) ? c1 : c0;
    u32 w1 = (q == 0) ? L23 : (q == 1) ? b2 : (q == 2) ? d1 : d0;
    u32 w2 = (q == 0) ? a0  : (q == 1) ? a1 : (q == 2) ? c2 : H01;
    u32 w3 = (q == 0) ? b0  : (q == 1) ? b1 : (q == 2) ? d2 : H23;
    s16x8 r;
    r[0] = (short)w0; r[1] = (short)(w0 >> 16);
    r[2] = (short)w1; r[3] = (short)(w1 >> 16);
    r[4] = (short)w2; r[5] = (short)(w2 >> 16);
    r[6] = (short)w3; r[7] = (short)(w3 >> 16);
    return r;
}

// R13: Phase-B weight matrices staged to LDS (dynamic smem, odd pitches ->
// conflict-free per-lane row reads). R12 lesson: per-lane global weight rows =
// 32-64 distinct cache lines per load instr -> TA serialization dominated.
__global__ __launch_bounds__(1024, 2)
void v2b_fused(const float* __restrict__ xl,    // (B,32,128)
               const float* __restrict__ xo,    // (B,32,64)
               const float* __restrict__ txyz,  // (B,64,3)
               const float* __restrict__ mlp_w1, const float* __restrict__ mlp_s1, const float* __restrict__ mlp_t1,
               const float* __restrict__ mlp_w2, const float* __restrict__ mlp_s2, const float* __restrict__ mlp_t2,
               const float* __restrict__ gw_w1, const float* __restrict__ gw_b1,
               const float* __restrict__ gw_s,  const float* __restrict__ gw_t,
               const float* __restrict__ gw_w2, const float* __restrict__ gw_b2,
               const float* __restrict__ gm_w1, const float* __restrict__ gm_s1, const float* __restrict__ gm_t1,
               const float* __restrict__ gm_w2, const float* __restrict__ gm_s2, const float* __restrict__ gm_t2,
               const float* __restrict__ fl_w1, const float* __restrict__ fl_s1, const float* __restrict__ fl_t1,
               const float* __restrict__ fl_w2, const float* __restrict__ fl_b2,
               float* __restrict__ out)
{
    __shared__ float xo_s[NF][P];
    __shared__ float yon_s[NF][P];       // -(gw_w1 . xo)
    __shared__ float tpos_s[NF][P];      // gm_t1 + gm_s1*(gm_w1[:,0:3] . txyz)
    __shared__ float txyz_s[3][NN1];
    __shared__ float xl_s[NF][MT];
    __shared__ float ylT_s[MT][NF];      // gw_w1 . xl + gw_b1, [m][c]
    __shared__ float na_s[NN1];
    __shared__ float nb_s[MT];
    __shared__ float gpart_s[MT][4][NF]; // per-(m,ng) gpool partials
    __shared__ float gws_s[NF], gwt_s[NF], gwb2_s[NF], gmt2_s[NF];
    __shared__ float ms1_s[32], mt1_s[32], ms2_s[32], mt2_s[32];
    __shared__ float fs1_s[64], ft1_s[64], fb2_s[64];
    __shared__ s16x8 afrag_s[2][6][64];  // duplicated: index by iter parity (anti-LICM)

    // dynamic LDS: Phase-B weights, odd pitches (conflict-free row reads)
    extern __shared__ float dynw[];
    float* W1 = dynw;                    // [32][69]
    float* W2 = W1 + 32 * 69;            // [32][33]
    float* F1 = W2 + 32 * 33;            // [64][65]
    float* F2 = F1 + 64 * 65;            // [64][65]

    const int b    = blockIdx.x >> 3;          // 128 batches
    const int m0   = (blockIdx.x & 7) * MT;    // 8 m-tiles of 16
    const int tid  = threadIdx.x;
    const int lane = tid & 63;
    const int w    = tid >> 6;                 // wave 0..15
    const int colr = lane & 15;
    const int q    = lane >> 4;

    // ---- stage inputs + weights (all coalesced) ----
    const float* xob = xo + (size_t)b * NF * NN1;
    for (int i = tid; i < NF * NN1; i += 1024) xo_s[i >> 6][i & 63] = xob[i];
    const float* tb = txyz + (size_t)b * NN1 * 3;
    if (tid < NN1 * 3) { int nn = tid / 3, k = tid % 3; txyz_s[k][nn] = tb[tid]; }
    if (tid < NF * MT) {
        int c = tid >> 4, j = tid & 15;
        xl_s[c][j] = xl[(size_t)b * NF * NN2 + c * NN2 + m0 + j];
    }
    if (tid >= 512 && tid < 512 + NF) {
        int c = tid - 512;
        gws_s[c]  = gw_s[c];
        gwt_s[c]  = gw_t[c];
        gwb2_s[c] = gw_b2[c];
        gmt2_s[c] = gm_t2[c];
    }
    if (tid >= 576 && tid < 576 + 32) {
        int c = tid - 576;
        ms1_s[c] = mlp_s1[c]; mt1_s[c] = mlp_t1[c];
        ms2_s[c] = mlp_s2[c]; mt2_s[c] = mlp_t2[c];
    }
    if (tid >= 640 && tid < 640 + 64) {
        int c = tid - 640;
        fs1_s[c] = fl_s1[c]; ft1_s[c] = fl_t1[c]; fb2_s[c] = fl_b2[c];
    }
    for (int i = tid; i < 32 * 68; i += 1024) W1[(i / 68) * 69 + (i % 68)] = mlp_w1[i];
    for (int i = tid; i < 32 * 32; i += 1024) W2[(i >> 5) * 33 + (i & 31)] = mlp_w2[i];
    for (int i = tid; i < 64 * 64; i += 1024) {
        int r = i >> 6, c = i & 63;
        F1[r * 65 + c] = fl_w1[i];
        F2[r * 65 + c] = fl_w2[i];
    }
    if (w >= 8 && w < 14) {   // A-frags
        const int f = w - 8;
        const int row = (f & 1) ? colr + 16 : colr;
        s16x8 a;
        if (f < 2) {
            #pragma unroll
            for (int j = 0; j < 8; ++j) a[j] = f2bf(gw_w2[row * 32 + 8 * q + j]);
        } else if (f < 4) {
            const float s1 = gm_s1[row];
            #pragma unroll
            for (int j = 0; j < 8; ++j) a[j] = f2bf(s1 * gm_w1[row * 35 + 3 + 8 * q + j]);
        } else {
            const float s2 = gm_s2[row];
            #pragma unroll
            for (int j = 0; j < 8; ++j) a[j] = f2bf(s2 * gm_w2[row * 32 + 8 * q + j]);
        }
        afrag_s[0][f][lane] = a;
        afrag_s[1][f][lane] = a;
    }
    __syncthreads();

    // ---- block precompute (fp32 exact) ----
    for (int i = tid; i < NF * NN1; i += 1024) {
        const int o = i >> 6, nn = i & 63;
        float s = 0.f;
        #pragma unroll
        for (int c = 0; c < NF; ++c) s += gw_w1[o * 32 + c] * xo_s[c][nn];
        yon_s[o][nn] = -s;
        float tp = gm_w1[o * 35 + 0] * txyz_s[0][nn]
                 + gm_w1[o * 35 + 1] * txyz_s[1][nn]
                 + gm_w1[o * 35 + 2] * txyz_s[2][nn];
        tpos_s[o][nn] = gm_s1[o] * tp + gm_t1[o];
    }
    if (tid < NF * MT) {
        const int j = tid >> 5, o = tid & 31;
        float s = gw_b1[o];
        #pragma unroll
        for (int c = 0; c < NF; ++c) s += gw_w1[o * 32 + c] * xl_s[c][j];
        ylT_s[j][o] = s;
    } else if (tid < NF * MT + NN1) {
        const int nn = tid - NF * MT;
        float s = 0.f;
        #pragma unroll
        for (int c = 0; c < NF; ++c) { float v = xo_s[c][nn]; s += v * v; }
        na_s[nn] = sqrtf(s);
    } else if (tid < NF * MT + NN1 + MT) {
        const int j = tid - NF * MT - NN1;
        float s = 0.f;
        #pragma unroll
        for (int c = 0; c < NF; ++c) { float v = xl_s[c][j]; s += v * v; }
        nb_s[j] = sqrtf(s);
    }
    __syncthreads();

    // ---- Phase A: 64 (m,ng) tasks over 16 waves ----
    for (int t = w; t < MT * 4; t += 16) {
        const int mj = t >> 2;
        const int ng = t & 3;
        const int n  = ng * 16 + colr;
        const s16x8* af = &afrag_s[(t >> 4) & 1][0][0];   // parity-indexed copy

        s16x8 bg;
        #pragma unroll
        for (int j = 0; j < 8; ++j) {
            const int k = 8 * q + j;
            float y = yon_s[k][n] + ylT_s[mj][k];
            float a = gws_s[k] * y + gwt_s[k];
            bg[j] = f2bf(a > 0.f ? a : 0.2f * a);
        }

        f32x4 zlo, zhi;
        #pragma unroll
        for (int r = 0; r < 4; ++r) { zlo[r] = gwb2_s[4 * q + r]; zhi[r] = gwb2_s[4 * q + r + 16]; }
        zlo = __builtin_amdgcn_mfma_f32_16x16x32_bf16(af[0 * 64 + lane], bg, zlo, 0, 0, 0);
        zhi = __builtin_amdgcn_mfma_f32_16x16x32_bf16(af[1 * 64 + lane], bg, zhi, 0, 0, 0);

        u32 L01, L23, H01, H23;
        {
            float d0 = xo_s[4 * q + 0][n] / (1.f + __expf(-zlo[0]));
            float d1 = xo_s[4 * q + 1][n] / (1.f + __expf(-zlo[1]));
            float d2 = xo_s[4 * q + 2][n] / (1.f + __expf(-zlo[2]));
            float d3 = xo_s[4 * q + 3][n] / (1.f + __expf(-zlo[3]));
            L01 = pack2(d0, d1); L23 = pack2(d2, d3);
            float e0 = xo_s[4 * q + 16][n] / (1.f + __expf(-zhi[0]));
            float e1 = xo_s[4 * q + 17][n] / (1.f + __expf(-zhi[1]));
            float e2 = xo_s[4 * q + 18][n] / (1.f + __expf(-zhi[2]));
            float e3 = xo_s[4 * q + 19][n] / (1.f + __expf(-zhi[3]));
            H01 = pack2(e0, e1); H23 = pack2(e2, e3);
        }
        s16x8 bga = redist(L01, L23, H01, H23, q);

        f32x4 mlo, mhi;
        #pragma unroll
        for (int r = 0; r < 4; ++r) { mlo[r] = tpos_s[4 * q + r][n]; mhi[r] = tpos_s[4 * q + r + 16][n]; }
        mlo = __builtin_amdgcn_mfma_f32_16x16x32_bf16(af[2 * 64 + lane], bga, mlo, 0, 0, 0);
        mhi = __builtin_amdgcn_mfma_f32_16x16x32_bf16(af[3 * 64 + lane], bga, mhi, 0, 0, 0);

        u32 M01 = pack2(fmaxf(mlo[0], 0.f), fmaxf(mlo[1], 0.f));
        u32 M23 = pack2(fmaxf(mlo[2], 0.f), fmaxf(mlo[3], 0.f));
        u32 N01 = pack2(fmaxf(mhi[0], 0.f), fmaxf(mhi[1], 0.f));
        u32 N23 = pack2(fmaxf(mhi[2], 0.f), fmaxf(mhi[3], 0.f));
        s16x8 bm1 = redist(M01, M23, N01, N23, q);

        f32x4 plo, phi;
        #pragma unroll
        for (int r = 0; r < 4; ++r) { plo[r] = gmt2_s[4 * q + r]; phi[r] = gmt2_s[4 * q + r + 16]; }
        plo = __builtin_amdgcn_mfma_f32_16x16x32_bf16(af[4 * 64 + lane], bm1, plo, 0, 0, 0);
        phi = __builtin_amdgcn_mfma_f32_16x16x32_bf16(af[5 * 64 + lane], bm1, phi, 0, 0, 0);

        float rmax[8];
        #pragma unroll
        for (int r = 0; r < 4; ++r) {
            rmax[r]     = fmaxf(plo[r], 0.f);
            rmax[r + 4] = fmaxf(phi[r], 0.f);
        }
        #pragma unroll
        for (int ix = 0; ix < 8; ++ix) {
            float v = rmax[ix];
            v = fmaxf(v, __shfl_xor(v, 1));
            v = fmaxf(v, __shfl_xor(v, 2));
            v = fmaxf(v, __shfl_xor(v, 4));
            v = fmaxf(v, __shfl_xor(v, 8));
            rmax[ix] = v;
        }
        if (colr == 0) {
            #pragma unroll
            for (int ix = 0; ix < 8; ++ix)
                gpart_s[mj][ng][4 * q + (ix & 3) + 16 * (ix >> 2)] = rmax[ix];
        }
    }
    __syncthreads();

    // ---- Phase B: all 16 waves, wave w = m-slot w; weights from LDS ----
    const int mj = w;
    const int m  = m0 + w;
    const int n  = lane;
    float num = 0.f;
    #pragma unroll
    for (int c = 0; c < NF; ++c) num += xo_s[c][n] * xl_s[c][mj];
    float cosv = num / fmaxf(na_s[n] * nb_s[mj], 1e-8f);
    float mv = cosv; int mi = n;
    #pragma unroll
    for (int s = 32; s > 0; s >>= 1) {
        float ov = __shfl_xor(mv, s);
        int   oi = __shfl_xor(mi, s);
        if (ov > mv || (ov == mv && oi < mi)) { mv = ov; mi = oi; }
    }

    const int oc = lane & 31;
    float h1;
    {
        const float* wp = W1 + oc * 69;
        float acc = wp[0] * mv;
        #pragma unroll
        for (int k = 0; k < 3; ++k)  acc += wp[1 + k]  * txyz_s[k][mi];
        #pragma unroll
        for (int c = 0; c < 32; ++c) acc += wp[4 + c]  * xo_s[c][mi];
        #pragma unroll
        for (int c = 0; c < 32; ++c) acc += wp[36 + c] * xl_s[c][mj];
        acc = ms1_s[oc] * acc + mt1_s[oc];
        h1 = acc > 0.f ? acc : 0.f;
    }
    float h2;
    {
        const float* wp = W2 + oc * 33;
        float acc = 0.f;
        #pragma unroll
        for (int c = 0; c < 32; ++c) acc += wp[c] * __shfl(h1, c);
        acc = ms2_s[oc] * acc + mt2_s[oc];
        h2 = acc > 0.f ? acc : 0.f;
    }
    float o1;
    {
        const float* wp = F1 + lane * 65;
        float acc = 0.f;
        #pragma unroll
        for (int c = 0; c < 32; ++c) acc += wp[c] * __shfl(h2, c);
        #pragma unroll
        for (int c = 0; c < 32; ++c) {
            float gv = fmaxf(fmaxf(gpart_s[mj][0][c], gpart_s[mj][1][c]),
                             fmaxf(gpart_s[mj][2][c], gpart_s[mj][3][c]));
            acc += wp[32 + c] * gv;
        }
        acc = fs1_s[lane] * acc + ft1_s[lane];
        o1 = acc > 0.f ? acc : 0.f;
    }
    {
        const float* wp = F2 + lane * 65;
        float acc = fb2_s[lane];
        #pragma unroll
        for (int c = 0; c < 64; ++c) acc += wp[c] * __shfl(o1, c);
        out[(size_t)b * 64 * NN2 + (size_t)lane * NN2 + m] = acc;
    }
}

extern "C" void kernel_launch(void* const* d_in, const int* in_sizes, int n_in,
                              void* d_out, int out_size, void* d_ws, size_t ws_size,
                              hipStream_t stream) {
    const float* xl     = (const float*)d_in[0];
    const float* xo     = (const float*)d_in[1];
    const float* txyz   = (const float*)d_in[2];
    const float* mlp_w1 = (const float*)d_in[3];
    const float* mlp_s1 = (const float*)d_in[4];
    const float* mlp_t1 = (const float*)d_in[5];
    const float* mlp_w2 = (const float*)d_in[6];
    const float* mlp_s2 = (const float*)d_in[7];
    const float* mlp_t2 = (const float*)d_in[8];
    const float* gw_w1  = (const float*)d_in[9];
    const float* gw_b1  = (const float*)d_in[10];
    const float* gw_s   = (const float*)d_in[11];
    const float* gw_t   = (const float*)d_in[12];
    const float* gw_w2  = (const float*)d_in[13];
    const float* gw_b2  = (const float*)d_in[14];
    const float* gm_w1  = (const float*)d_in[15];
    const float* gm_s1  = (const float*)d_in[16];
    const float* gm_t1  = (const float*)d_in[17];
    const float* gm_w2  = (const float*)d_in[18];
    const float* gm_s2  = (const float*)d_in[19];
    const float* gm_t2  = (const float*)d_in[20];
    const float* fl_w1  = (const float*)d_in[21];
    const float* fl_s1  = (const float*)d_in[22];
    const float* fl_t1  = (const float*)d_in[23];
    const float* fl_w2  = (const float*)d_in[24];
    const float* fl_b2  = (const float*)d_in[25];
    float* outp = (float*)d_out;

    const int B = in_sizes[0] / (NF * NN2);   // 128
    const size_t dyn = (size_t)(32 * 69 + 32 * 33 + 64 * 65 + 64 * 65) * sizeof(float); // 46336 B
    v2b_fused<<<dim3(B * 8), 1024, dyn, stream>>>(
        xl, xo, txyz,
        mlp_w1, mlp_s1, mlp_t1, mlp_w2, mlp_s2, mlp_t2,
        gw_w1, gw_b1, gw_s, gw_t, gw_w2, gw_b2,
        gm_w1, gm_s1, gm_t1, gm_w2, gm_s2, gm_t2,
        fl_w1, fl_s1, fl_t1, fl_w2, fl_b2,
        outp);
}

// Round 14
// 231.206 us; speedup vs baseline: 1.4128x; 1.0393x over previous
//
#include <hip/hip_runtime.h>

#define NF   32
#define NN1  64
#define NN2  128
#define MT   16    // m per block
#define P    66    // fp32 tile pitch
#define PU   66    // ushort tile pitch (bf16 rows)

typedef float f32x4 __attribute__((ext_vector_type(4)));
typedef short s16x8 __attribute__((ext_vector_type(8)));
typedef unsigned int u32;
typedef unsigned short ushort;

__device__ __forceinline__ short f2bf(float f) {   // fp32 -> bf16, RNE
    u32 u = __float_as_uint(f);
    return (short)((u + 0x7FFFu + ((u >> 16) & 1u)) >> 16);
}
__device__ __forceinline__ float b2f(ushort us) {  // bf16 bits -> fp32
    return __uint_as_float((u32)us << 16);
}
__device__ __forceinline__ u32 pack2(float a, float b) {
    return (u32)(ushort)f2bf(a) | ((u32)(ushort)f2bf(b) << 16);
}

// D->B redistribution, XOR-only (validated R11-R13, absmax 1.95e-3)
__device__ __forceinline__ s16x8 redist(u32 L01, u32 L23, u32 H01, u32 H23, int q) {
    u32 a0 = __shfl_xor((int)L01, 16), a1 = __shfl_xor((int)L01, 32), a2 = __shfl_xor((int)L01, 48);
    u32 b0 = __shfl_xor((int)L23, 16), b1 = __shfl_xor((int)L23, 32), b2 = __shfl_xor((int)L23, 48);
    u32 c0 = __shfl_xor((int)H01, 16), c1 = __shfl_xor((int)H01, 32), c2 = __shfl_xor((int)H01, 48);
    u32 d0 = __shfl_xor((int)H23, 16), d1 = __shfl_xor((int)H23, 32), d2 = __shfl_xor((int)H23, 48);
    u32 w0 = (q == 0) ? L01 : (q == 1) ? a2 : (q == 2) ? c1 : c0;
    u32 w1 = (q == 0) ? L23 : (q == 1) ? b2 : (q == 2) ? d1 : d0;
    u32 w2 = (q == 0) ? a0  : (q == 1) ? a1 : (q == 2) ? c2 : H01;
    u32 w3 = (q == 0) ? b0  : (q == 1) ? b1 : (q == 2) ? d2 : H23;
    s16x8 r;
    r[0] = (short)w0; r[1] = (short)(w0 >> 16);
    r[2] = (short)w1; r[3] = (short)(w1 >> 16);
    r[4] = (short)w2; r[5] = (short)(w2 >> 16);
    r[6] = (short)w3; r[7] = (short)(w3 >> 16);
    return r;
}

// R14: LDS cut to ~74 KB total (yon/tpos + W1/W2/F1 as bf16) -> 2 blocks/CU
// (R13 lesson: 100 KB -> 1 block/CU capped occupancy at 40%, latency exposed).
__global__ __launch_bounds__(1024, 2)
void v2b_fused(const float* __restrict__ xl,    // (B,32,128)
               const float* __restrict__ xo,    // (B,32,64)
               const float* __restrict__ txyz,  // (B,64,3)
               const float* __restrict__ mlp_w1, const float* __restrict__ mlp_s1, const float* __restrict__ mlp_t1,
               const float* __restrict__ mlp_w2, const float* __restrict__ mlp_s2, const float* __restrict__ mlp_t2,
               const float* __restrict__ gw_w1, const float* __restrict__ gw_b1,
               const float* __restrict__ gw_s,  const float* __restrict__ gw_t,
               const float* __restrict__ gw_w2, const float* __restrict__ gw_b2,
               const float* __restrict__ gm_w1, const float* __restrict__ gm_s1, const float* __restrict__ gm_t1,
               const float* __restrict__ gm_w2, const float* __restrict__ gm_s2, const float* __restrict__ gm_t2,
               const float* __restrict__ fl_w1, const float* __restrict__ fl_s1, const float* __restrict__ fl_t1,
               const float* __restrict__ fl_w2, const float* __restrict__ fl_b2,
               float* __restrict__ out)
{
    __shared__ float  xo_s[NF][P];
    __shared__ ushort yon_us[NF * PU];     // bf16: -(gw_w1 . xo)
    __shared__ ushort tpos_us[NF * PU];    // bf16: gm_t1 + gm_s1*(gm_w1[:,0:3].txyz)
    __shared__ float  txyz_s[3][NN1];
    __shared__ float  xl_s[NF][MT];
    __shared__ float  ylT_s[MT][NF];       // gw_w1 . xl + gw_b1, [m][c] (fp32)
    __shared__ float  na_s[NN1];
    __shared__ float  nb_s[MT];
    __shared__ float  gpart_s[MT][4][NF];  // per-(m,ng) gpool partials
    __shared__ float  gws_s[NF], gwt_s[NF], gwb2_s[NF], gmt2_s[NF];
    __shared__ float  ms1_s[32], mt1_s[32], ms2_s[32], mt2_s[32];
    __shared__ float  fs1_s[64], ft1_s[64], fb2_s[64];
    __shared__ s16x8  afrag_s[2][6][64];   // duplicated: iter-parity indexed (anti-LICM, R12-proven)

    // dynamic LDS: F2 fp32 (final layer, precision) + bf16 W1/W2/F1
    extern __shared__ float dynw[];
    float*  F2   = dynw;                        // [64][65] fp32
    ushort* W1us = (ushort*)(F2 + 64 * 65);     // [32][70] bf16
    ushort* W2us = W1us + 32 * 70;              // [32][34] bf16
    ushort* F1us = W2us + 32 * 34;              // [64][66] bf16

    const int b    = blockIdx.x >> 3;          // 128 batches
    const int m0   = (blockIdx.x & 7) * MT;    // 8 m-tiles of 16
    const int tid  = threadIdx.x;
    const int lane = tid & 63;
    const int w    = tid >> 6;                 // wave 0..15
    const int colr = lane & 15;
    const int q    = lane >> 4;

    // ---- stage inputs + weights (all coalesced) ----
    const float* xob = xo + (size_t)b * NF * NN1;
    for (int i = tid; i < NF * NN1; i += 1024) xo_s[i >> 6][i & 63] = xob[i];
    const float* tb = txyz + (size_t)b * NN1 * 3;
    if (tid < NN1 * 3) { int nn = tid / 3, k = tid % 3; txyz_s[k][nn] = tb[tid]; }
    if (tid < NF * MT) {
        int c = tid >> 4, j = tid & 15;
        xl_s[c][j] = xl[(size_t)b * NF * NN2 + c * NN2 + m0 + j];
    }
    if (tid >= 512 && tid < 512 + NF) {
        int c = tid - 512;
        gws_s[c]  = gw_s[c];
        gwt_s[c]  = gw_t[c];
        gwb2_s[c] = gw_b2[c];
        gmt2_s[c] = gm_t2[c];
    }
    if (tid >= 576 && tid < 576 + 32) {
        int c = tid - 576;
        ms1_s[c] = mlp_s1[c]; mt1_s[c] = mlp_t1[c];
        ms2_s[c] = mlp_s2[c]; mt2_s[c] = mlp_t2[c];
    }
    if (tid >= 640 && tid < 640 + 64) {
        int c = tid - 640;
        fs1_s[c] = fl_s1[c]; ft1_s[c] = fl_t1[c]; fb2_s[c] = fl_b2[c];
    }
    for (int i = tid; i < 32 * 68; i += 1024) W1us[(i / 68) * 70 + (i % 68)] = (ushort)f2bf(mlp_w1[i]);
    for (int i = tid; i < 32 * 32; i += 1024) W2us[(i >> 5) * 34 + (i & 31)] = (ushort)f2bf(mlp_w2[i]);
    for (int i = tid; i < 64 * 64; i += 1024) {
        int r = i >> 6, c = i & 63;
        F1us[r * 66 + c] = (ushort)f2bf(fl_w1[i]);
        F2[r * 65 + c]   = fl_w2[i];
    }
    if (w >= 8 && w < 14) {   // A-frags
        const int f = w - 8;
        const int row = (f & 1) ? colr + 16 : colr;
        s16x8 a;
        if (f < 2) {
            #pragma unroll
            for (int j = 0; j < 8; ++j) a[j] = f2bf(gw_w2[row * 32 + 8 * q + j]);
        } else if (f < 4) {
            const float s1 = gm_s1[row];
            #pragma unroll
            for (int j = 0; j < 8; ++j) a[j] = f2bf(s1 * gm_w1[row * 35 + 3 + 8 * q + j]);
        } else {
            const float s2 = gm_s2[row];
            #pragma unroll
            for (int j = 0; j < 8; ++j) a[j] = f2bf(s2 * gm_w2[row * 32 + 8 * q + j]);
        }
        afrag_s[0][f][lane] = a;
        afrag_s[1][f][lane] = a;
    }
    __syncthreads();

    // ---- block precompute ----
    for (int i = tid; i < NF * NN1; i += 1024) {
        const int o = i >> 6, nn = i & 63;
        float s = 0.f;
        #pragma unroll
        for (int c = 0; c < NF; ++c) s += gw_w1[o * 32 + c] * xo_s[c][nn];
        yon_us[o * PU + nn] = (ushort)f2bf(-s);
        float tp = gm_w1[o * 35 + 0] * txyz_s[0][nn]
                 + gm_w1[o * 35 + 1] * txyz_s[1][nn]
                 + gm_w1[o * 35 + 2] * txyz_s[2][nn];
        tpos_us[o * PU + nn] = (ushort)f2bf(gm_s1[o] * tp + gm_t1[o]);
    }
    if (tid < NF * MT) {
        const int j = tid >> 5, o = tid & 31;
        float s = gw_b1[o];
        #pragma unroll
        for (int c = 0; c < NF; ++c) s += gw_w1[o * 32 + c] * xl_s[c][j];
        ylT_s[j][o] = s;
    } else if (tid < NF * MT + NN1) {
        const int nn = tid - NF * MT;
        float s = 0.f;
        #pragma unroll
        for (int c = 0; c < NF; ++c) { float v = xo_s[c][nn]; s += v * v; }
        na_s[nn] = sqrtf(s);
    } else if (tid < NF * MT + NN1 + MT) {
        const int j = tid - NF * MT - NN1;
        float s = 0.f;
        #pragma unroll
        for (int c = 0; c < NF; ++c) { float v = xl_s[c][j]; s += v * v; }
        nb_s[j] = sqrtf(s);
    }
    __syncthreads();

    // ---- Phase A: 64 (m,ng) tasks over 16 waves ----
    for (int t = w; t < MT * 4; t += 16) {
        const int mj = t >> 2;
        const int ng = t & 3;
        const int n  = ng * 16 + colr;
        const s16x8* af = &afrag_s[(t >> 4) & 1][0][0];   // parity-indexed copy

        s16x8 bg;
        #pragma unroll
        for (int j = 0; j < 8; ++j) {
            const int k = 8 * q + j;
            float y = b2f(yon_us[k * PU + n]) + ylT_s[mj][k];
            float a = gws_s[k] * y + gwt_s[k];
            bg[j] = f2bf(a > 0.f ? a : 0.2f * a);
        }

        f32x4 zlo, zhi;
        #pragma unroll
        for (int r = 0; r < 4; ++r) { zlo[r] = gwb2_s[4 * q + r]; zhi[r] = gwb2_s[4 * q + r + 16]; }
        zlo = __builtin_amdgcn_mfma_f32_16x16x32_bf16(af[0 * 64 + lane], bg, zlo, 0, 0, 0);
        zhi = __builtin_amdgcn_mfma_f32_16x16x32_bf16(af[1 * 64 + lane], bg, zhi, 0, 0, 0);

        u32 L01, L23, H01, H23;
        {
            float d0 = xo_s[4 * q + 0][n] / (1.f + __expf(-zlo[0]));
            float d1 = xo_s[4 * q + 1][n] / (1.f + __expf(-zlo[1]));
            float d2 = xo_s[4 * q + 2][n] / (1.f + __expf(-zlo[2]));
            float d3 = xo_s[4 * q + 3][n] / (1.f + __expf(-zlo[3]));
            L01 = pack2(d0, d1); L23 = pack2(d2, d3);
            float e0 = xo_s[4 * q + 16][n] / (1.f + __expf(-zhi[0]));
            float e1 = xo_s[4 * q + 17][n] / (1.f + __expf(-zhi[1]));
            float e2 = xo_s[4 * q + 18][n] / (1.f + __expf(-zhi[2]));
            float e3 = xo_s[4 * q + 19][n] / (1.f + __expf(-zhi[3]));
            H01 = pack2(e0, e1); H23 = pack2(e2, e3);
        }
        s16x8 bga = redist(L01, L23, H01, H23, q);

        f32x4 mlo, mhi;
        #pragma unroll
        for (int r = 0; r < 4; ++r) {
            mlo[r] = b2f(tpos_us[(4 * q + r) * PU + n]);
            mhi[r] = b2f(tpos_us[(4 * q + r + 16) * PU + n]);
        }
        mlo = __builtin_amdgcn_mfma_f32_16x16x32_bf16(af[2 * 64 + lane], bga, mlo, 0, 0, 0);
        mhi = __builtin_amdgcn_mfma_f32_16x16x32_bf16(af[3 * 64 + lane], bga, mhi, 0, 0, 0);

        u32 M01 = pack2(fmaxf(mlo[0], 0.f), fmaxf(mlo[1], 0.f));
        u32 M23 = pack2(fmaxf(mlo[2], 0.f), fmaxf(mlo[3], 0.f));
        u32 N01 = pack2(fmaxf(mhi[0], 0.f), fmaxf(mhi[1], 0.f));
        u32 N23 = pack2(fmaxf(mhi[2], 0.f), fmaxf(mhi[3], 0.f));
        s16x8 bm1 = redist(M01, M23, N01, N23, q);

        f32x4 plo, phi;
        #pragma unroll
        for (int r = 0; r < 4; ++r) { plo[r] = gmt2_s[4 * q + r]; phi[r] = gmt2_s[4 * q + r + 16]; }
        plo = __builtin_amdgcn_mfma_f32_16x16x32_bf16(af[4 * 64 + lane], bm1, plo, 0, 0, 0);
        phi = __builtin_amdgcn_mfma_f32_16x16x32_bf16(af[5 * 64 + lane], bm1, phi, 0, 0, 0);

        float rmax[8];
        #pragma unroll
        for (int r = 0; r < 4; ++r) {
            rmax[r]     = fmaxf(plo[r], 0.f);
            rmax[r + 4] = fmaxf(phi[r], 0.f);
        }
        #pragma unroll
        for (int ix = 0; ix < 8; ++ix) {
            float v = rmax[ix];
            v = fmaxf(v, __shfl_xor(v, 1));
            v = fmaxf(v, __shfl_xor(v, 2));
            v = fmaxf(v, __shfl_xor(v, 4));
            v = fmaxf(v, __shfl_xor(v, 8));
            rmax[ix] = v;
        }
        if (colr == 0) {
            #pragma unroll
            for (int ix = 0; ix < 8; ++ix)
                gpart_s[mj][ng][4 * q + (ix & 3) + 16 * (ix >> 2)] = rmax[ix];
        }
    }
    __syncthreads();

    // ---- Phase B: all 16 waves, wave w = m-slot w; weights from LDS ----
    const int mj = w;
    const int m  = m0 + w;
    const int n  = lane;
    float num = 0.f;
    #pragma unroll
    for (int c = 0; c < NF; ++c) num += xo_s[c][n] * xl_s[c][mj];
    float cosv = num / fmaxf(na_s[n] * nb_s[mj], 1e-8f);
    float mv = cosv; int mi = n;
    #pragma unroll
    for (int s = 32; s > 0; s >>= 1) {
        float ov = __shfl_xor(mv, s);
        int   oi = __shfl_xor(mi, s);
        if (ov > mv || (ov == mv && oi < mi)) { mv = ov; mi = oi; }
    }

    const int oc = lane & 31;
    float h1;
    {
        const ushort* wp = W1us + oc * 70;
        float acc = b2f(wp[0]) * mv;
        #pragma unroll
        for (int k = 0; k < 3; ++k)  acc += b2f(wp[1 + k])  * txyz_s[k][mi];
        #pragma unroll
        for (int c = 0; c < 32; ++c) acc += b2f(wp[4 + c])  * xo_s[c][mi];
        #pragma unroll
        for (int c = 0; c < 32; ++c) acc += b2f(wp[36 + c]) * xl_s[c][mj];
        acc = ms1_s[oc] * acc + mt1_s[oc];
        h1 = acc > 0.f ? acc : 0.f;
    }
    float h2;
    {
        const ushort* wp = W2us + oc * 34;
        float acc = 0.f;
        #pragma unroll
        for (int c = 0; c < 32; ++c) acc += b2f(wp[c]) * __shfl(h1, c);
        acc = ms2_s[oc] * acc + mt2_s[oc];
        h2 = acc > 0.f ? acc : 0.f;
    }
    float o1;
    {
        const ushort* wp = F1us + lane * 66;
        float acc = 0.f;
        #pragma unroll
        for (int c = 0; c < 32; ++c) acc += b2f(wp[c]) * __shfl(h2, c);
        #pragma unroll
        for (int c = 0; c < 32; ++c) {
            float gv = fmaxf(fmaxf(gpart_s[mj][0][c], gpart_s[mj][1][c]),
                             fmaxf(gpart_s[mj][2][c], gpart_s[mj][3][c]));
            acc += b2f(wp[32 + c]) * gv;
        }
        acc = fs1_s[lane] * acc + ft1_s[lane];
        o1 = acc > 0.f ? acc : 0.f;
    }
    {
        const float* wp = F2 + lane * 65;
        float acc = fb2_s[lane];
        #pragma unroll
        for (int c = 0; c < 64; ++c) acc += wp[c] * __shfl(o1, c);
        out[(size_t)b * 64 * NN2 + (size_t)lane * NN2 + m] = acc;
    }
}

extern "C" void kernel_launch(void* const* d_in, const int* in_sizes, int n_in,
                              void* d_out, int out_size, void* d_ws, size_t ws_size,
                              hipStream_t stream) {
    const float* xl     = (const float*)d_in[0];
    const float* xo     = (const float*)d_in[1];
    const float* txyz   = (const float*)d_in[2];
    const float* mlp_w1 = (const float*)d_in[3];
    const float* mlp_s1 = (const float*)d_in[4];
    const float* mlp_t1 = (const float*)d_in[5];
    const float* mlp_w2 = (const float*)d_in[6];
    const float* mlp_s2 = (const float*)d_in[7];
    const float* mlp_t2 = (const float*)d_in[8];
    const float* gw_w1  = (const float*)d_in[9];
    const float* gw_b1  = (const float*)d_in[10];
    const float* gw_s   = (const float*)d_in[11];
    const float* gw_t   = (const float*)d_in[12];
    const float* gw_w2  = (const float*)d_in[13];
    const float* gw_b2  = (const float*)d_in[14];
    const float* gm_w1  = (const float*)d_in[15];
    const float* gm_s1  = (const float*)d_in[16];
    const float* gm_t1  = (const float*)d_in[17];
    const float* gm_w2  = (const float*)d_in[18];
    const float* gm_s2  = (const float*)d_in[19];
    const float* gm_t2  = (const float*)d_in[20];
    const float* fl_w1  = (const float*)d_in[21];
    const float* fl_s1  = (const float*)d_in[22];
    const float* fl_t1  = (const float*)d_in[23];
    const float* fl_w2  = (const float*)d_in[24];
    const float* fl_b2  = (const float*)d_in[25];
    float* outp = (float*)d_out;

    const int B = in_sizes[0] / (NF * NN2);   // 128
    const size_t dyn = (size_t)(64 * 65) * sizeof(float)
                     + (size_t)(32 * 70 + 32 * 34 + 64 * 66) * sizeof(ushort); // 31744 B
    v2b_fused<<<dim3(B * 8), 1024, dyn, stream>>>(
        xl, xo, txyz,
        mlp_w1, mlp_s1, mlp_t1, mlp_w2, mlp_s2, mlp_t2,
        gw_w1, gw_b1, gw_s, gw_t, gw_w2, gw_b2,
        gm_w1, gm_s1, gm_t1, gm_w2, gm_s2, gm_t2,
        fl_w1, fl_s1, fl_t1, fl_w2, fl_b2,
        outp);
}